// Round 2
// baseline (597.652 us; speedup 1.0000x reference)
//
#include <hip/hip_runtime.h>
#include <cmath>

// ---------------------------------------------------------------------------
// HyperbolicScaleHead — round 4.
// Structure: softmax over seqlen-1 == identity => attn_out = t@(Wv@Wo)+b.
// Fold: pre1 = h @ (W2@(I+Wv@Wo)) + (b2@(I+Wv@Wo)+bc) -- one GEMM, LN1 fused.
// Pipeline (7 launches):
//   k_prep   : cvt x->bf16, transpose W1/fw1/fw2/euc_w, protos clip+norms
//   k_fold   : W2''^T = (W2@(I+Wv@Wo))^T bf16, b''
//   GEMM1    : gelu(x@W1+b1) -> bf16               (4096x256x1024)
//   GEMM2    : h@W2''+b'' -> LN1 epilogue          (4096x128x256)
//   FFN1     : gelu(xs1@fw1+fb1) -> bf16           (4096x512x128)
//   FFN2     : xs1 + h2@fw2+fb2 -> LN2+Poincare    (4096x128x512)
//   k_heads  : hyp + euc logits fused              (4096x(2x10112)x128)
// R4: k_heads rewritten as persistent col-loop: grid (32,16), A in 64 VGPRs
//     (loaded once per head phase), B double-buffered in 64KB LDS, counted
//     vmcnt(32) 2-phase pipeline (stage issued mid-epilogue so exactly 32
//     stores are younger than it), fast-math arccosh epilogue (rcp/sqrt/log).
//     t_cvt transpose stores vectorized to ushort2.
// ---------------------------------------------------------------------------

using bf16x8 = __attribute__((ext_vector_type(8))) __bf16;
using f32x4  = __attribute__((ext_vector_type(4))) float;

#define DEVINL __device__ __forceinline__

DEVINL unsigned short f2b(float f) {
    unsigned int u = __builtin_bit_cast(unsigned int, f);
    u = (u + 0x7fffu + ((u >> 16) & 1u)) >> 16;
    return (unsigned short)u;
}

DEVINL float gelu_exact(float x) {
    return 0.5f * x * (1.0f + erff(x * 0.70710678118654752440f));
}

DEVINL float get_c(const float* logc) {
    float c = expf(logc[0]);
    c = fminf(fmaxf(c, 1e-4f), 10.0f);
    return fmaxf(fabsf(c), 1e-6f);
}

DEVINL void async16(const unsigned short* g, unsigned short* l) {
    __builtin_amdgcn_global_load_lds(
        (const __attribute__((address_space(1))) void*)g,
        (__attribute__((address_space(3))) void*)l, 16, 0, 0);
}

// --------------------------- prep mega-kernel ------------------------------

DEVINL void t_cvt(const float* __restrict__ src, unsigned short* __restrict__ dst,
                  int K, int N, int Npad, int ld, int off, int tblk, int tid,
                  float tile[32][33]) {
    int kbCount = K >> 5;
    int kb = (tblk % kbCount) * 32, nb = (tblk / kbCount) * 32;
    int tx = tid & 31, ty = tid >> 5;
    #pragma unroll
    for (int i = 0; i < 32; i += 8) {
        int k = kb + ty + i, n = nb + tx;
        tile[ty + i][tx] = (k < K && n < N) ? src[(size_t)k * ld + off + n] : 0.0f;
    }
    __syncthreads();
    // vectorized write-out: each thread writes ushort2 (2 consecutive k)
    int tx2 = (tid & 15) * 2, ty2 = tid >> 4;
    #pragma unroll
    for (int i = 0; i < 32; i += 16) {
        int n = nb + ty2 + i, k = kb + tx2;
        if (n < Npad && k + 1 < K + 1) {  // K multiple of 32 -> pair always in-range
            ushort2 o2;
            o2.x = f2b(tile[tx2][ty2 + i]);
            o2.y = f2b(tile[tx2 + 1][ty2 + i]);
            *(ushort2*)&dst[(size_t)n * K + k] = o2;
        }
    }
}

// block ranges: [0,4096) cvt x | +256 W1 | +64 fw1 | +64 fw2 | +1264 euc_w | +2528 protos
#define PB0 4096
#define PB1 (PB0 + 256)
#define PB2 (PB1 + 64)
#define PB3 (PB2 + 64)
#define PB4 (PB3 + 1264)
#define PB5 (PB4 + 2528)

__global__ void k_prep(const float* __restrict__ x, const float* __restrict__ W1,
                       const float* __restrict__ fw1, const float* __restrict__ fw2,
                       const float* __restrict__ euc_w, const float* __restrict__ P,
                       const float* __restrict__ logc,
                       unsigned short* __restrict__ xbf, unsigned short* __restrict__ W1T,
                       unsigned short* __restrict__ FW1T, unsigned short* __restrict__ FW2T,
                       unsigned short* __restrict__ EUCWT, unsigned short* __restrict__ PROTB,
                       float* __restrict__ p2a, float* __restrict__ dpa) {
    __shared__ float tile[32][33];
    int b = blockIdx.x, tid = threadIdx.x;
    if (b < PB0) {
        int i = b * 256 + tid;
        float4 v = ((const float4*)x)[i];
        ushort4 o;
        o.x = f2b(v.x); o.y = f2b(v.y); o.z = f2b(v.z); o.w = f2b(v.w);
        ((ushort4*)xbf)[i] = o;
    } else if (b < PB1) {
        t_cvt(W1, W1T, 1024, 256, 256, 256, 0, b - PB0, tid, tile);
    } else if (b < PB2) {
        t_cvt(fw1, FW1T, 128, 512, 512, 512, 0, b - PB1, tid, tile);
    } else if (b < PB3) {
        t_cvt(fw2, FW2T, 512, 128, 128, 128, 0, b - PB2, tid, tile);
    } else if (b < PB4) {
        t_cvt(euc_w, EUCWT, 128, 10000, 10112, 10000, 0, b - PB3, tid, tile);
    } else {
        int lane = tid & 63;
        int row = (b - PB4) * 4 + (tid >> 6);
        size_t base = (size_t)row * 128;
        if (row < 10000) {
            float a = P[base + lane], bb = P[base + 64 + lane];
            float n2 = a * a + bb * bb;
            #pragma unroll
            for (int m = 32; m > 0; m >>= 1) n2 += __shfl_xor(n2, m, 64);
            float c = get_c(logc);
            float sq = sqrtf(c);
            float mx = (1.0f - 1e-5f) / sq;
            float pn = sqrtf(n2);
            float f = fminf(mx / fmaxf(pn, 1e-6f), 1.0f);
            a *= f; bb *= f;
            PROTB[base + lane] = f2b(a); PROTB[base + 64 + lane] = f2b(bb);
            if (lane == 0) {
                float p2 = n2 * f * f;
                p2a[row] = p2;
                dpa[row] = 1.0f - c * fminf(p2, 1.0f - 1e-5f);
            }
        } else if (row < 10112) {
            PROTB[base + lane] = 0; PROTB[base + 64 + lane] = 0;
            if (lane == 0) { p2a[row] = 0.0f; dpa[row] = 1.0f; }
        }
    }
}

// --------------------------- fold kernel (merged) --------------------------
__global__ void k_fold(const float* __restrict__ in_w, const float* __restrict__ in_b,
                       const float* __restrict__ out_w, const float* __restrict__ out_b,
                       const float* __restrict__ W2, const float* __restrict__ b2,
                       unsigned short* __restrict__ W2ppT, float* __restrict__ bpp) {
    __shared__ float WoCol[128];
    __shared__ float WcCol[128];
    const int n = blockIdx.x, t = threadIdx.x;
    WoCol[t] = out_w[t * 128 + n];
    __syncthreads();
    float a = (t == n) ? 1.0f : 0.0f;
    for (int j = 0; j < 128; j++) a += in_w[t * 384 + 256 + j] * WoCol[j];
    WcCol[t] = a;
    __syncthreads();
    #pragma unroll
    for (int h = 0; h < 2; h++) {
        int k = t + h * 128;
        float s = 0.f;
        for (int j = 0; j < 128; j++) s += W2[k * 128 + j] * WcCol[j];
        W2ppT[n * 256 + k] = f2b(s);
    }
    if (t == 0) {
        float s = 0.f;
        for (int j = 0; j < 128; j++) s += b2[j] * WcCol[j];
        float s2 = 0.f;
        for (int j = 0; j < 128; j++) s2 += in_b[256 + j] * WoCol[j];
        bpp[n] = s + s2 + out_b[n];
    }
}

// --------------------------- GEMM + fused epilogues ------------------------
#define EP_GELU 0
#define EP_LN1 1
#define EP_LN2HYP 2

template <int EP, int BK>
__global__ __launch_bounds__(256) void k_gemm(
    const unsigned short* __restrict__ A, const unsigned short* __restrict__ Bm,
    const float* __restrict__ bias, int K, int Nstore,
    float* __restrict__ outF, unsigned short* __restrict__ outH,
    const float* __restrict__ g, const float* __restrict__ bt,
    const float* __restrict__ resF, const float* __restrict__ logc,
    float* __restrict__ embF, unsigned short* __restrict__ embH,
    float* __restrict__ e2a, float* __restrict__ dea) {
    __shared__ __align__(16) unsigned short As[128 * BK];
    __shared__ __align__(16) unsigned short Bs[128 * BK];
    const int tid = threadIdx.x, lane = tid & 63, wid = tid >> 6;
    const int row0 = blockIdx.x * 128, col0 = blockIdx.y * 128;
    const int q = lane >> 4, l16 = lane & 15;
    const int wm = (wid >> 1) * 64, wn = (wid & 1) * 64;
    const int sw = (l16 & 7) * 8;
    constexpr int CPR = BK / 8;
    constexpr int ITER = 128 * CPR / 256;

    f32x4 acc[4][4];
    #pragma unroll
    for (int i = 0; i < 4; i++)
        #pragma unroll
        for (int j = 0; j < 4; j++) acc[i][j] = {0.f, 0.f, 0.f, 0.f};

    for (int k0 = 0; k0 < K; k0 += BK) {
        #pragma unroll
        for (int it = 0; it < ITER; ++it) {
            int idx = it * 256 + tid;
            int r = idx / CPR, ck = (idx % CPR) * 8;
            int cks = ck ^ ((r & 7) * 8);
            async16(&A[(size_t)(row0 + r) * K + k0 + cks], &As[idx * 8]);
        }
        #pragma unroll
        for (int it = 0; it < ITER; ++it) {
            int idx = it * 256 + tid;
            int r = idx / CPR, ck = (idx % CPR) * 8;
            int cks = ck ^ ((r & 7) * 8);
            async16(&Bm[(size_t)(col0 + r) * K + k0 + cks], &Bs[idx * 8]);
        }
        __syncthreads();
        #pragma unroll
        for (int kk = 0; kk < BK; kk += 32) {
            bf16x8 af[4], bfr[4];
            #pragma unroll
            for (int i = 0; i < 4; i++)
                af[i] = *(const bf16x8*)&As[(wm + i * 16 + l16) * BK + ((kk + q * 8) ^ sw)];
            #pragma unroll
            for (int j = 0; j < 4; j++)
                bfr[j] = *(const bf16x8*)&Bs[(wn + j * 16 + l16) * BK + ((kk + q * 8) ^ sw)];
            #pragma unroll
            for (int i = 0; i < 4; i++)
                #pragma unroll
                for (int j = 0; j < 4; j++)
                    acc[i][j] = __builtin_amdgcn_mfma_f32_16x16x32_bf16(
                        af[i], bfr[j], acc[i][j], 0, 0, 0);
        }
        __syncthreads();
    }

    if (EP == EP_GELU) {
        #pragma unroll
        for (int j = 0; j < 4; j++) {
            int col = col0 + wn + j * 16 + l16;
            float bb = bias[col];
            #pragma unroll
            for (int i = 0; i < 4; i++)
                #pragma unroll
                for (int rg = 0; rg < 4; rg++) {
                    int row = row0 + wm + i * 16 + q * 4 + rg;
                    outH[(size_t)row * Nstore + col] = f2b(gelu_exact(acc[i][j][rg] + bb));
                }
        }
        return;
    }

    #pragma unroll
    for (int j = 0; j < 4; j++) {
        int col = wn + j * 16 + l16;
        float bb = bias[col];
        #pragma unroll
        for (int i = 0; i < 4; i++)
            #pragma unroll
            for (int rg = 0; rg < 4; rg++) {
                int rl = wm + i * 16 + q * 4 + rg;
                float v = acc[i][j][rg] + bb;
                if (EP == EP_LN2HYP) v += resF[(size_t)(row0 + rl) * 128 + col];
                acc[i][j][rg] = v;
            }
    }
    float* sred = (float*)As;
    #pragma unroll
    for (int i = 0; i < 4; i++)
        #pragma unroll
        for (int rg = 0; rg < 4; rg++) {
            float s = 0.f, ss = 0.f;
            #pragma unroll
            for (int j = 0; j < 4; j++) { float v = acc[i][j][rg]; s += v; ss += v * v; }
            #pragma unroll
            for (int m = 1; m < 16; m <<= 1) {
                s += __shfl_xor(s, m, 64); ss += __shfl_xor(ss, m, 64);
            }
            if (l16 == 0) {
                int rl = wm + i * 16 + q * 4 + rg;
                sred[rl * 4 + (wid & 1) * 2] = s;
                sred[rl * 4 + (wid & 1) * 2 + 1] = ss;
            }
        }
    __syncthreads();

    float c = 0.f, sq = 0.f, mx = 0.f;
    if (EP == EP_LN2HYP) { c = get_c(logc); sq = sqrtf(c); mx = (1.0f - 1e-5f) / sq; }

    #pragma unroll
    for (int i = 0; i < 4; i++)
        #pragma unroll
        for (int rg = 0; rg < 4; rg++) {
            int rl = wm + i * 16 + q * 4 + rg;
            int row = row0 + rl;
            float sum = sred[rl * 4 + 0] + sred[rl * 4 + 2];
            float sqs = sred[rl * 4 + 1] + sred[rl * 4 + 3];
            float m = sum * (1.0f / 128.0f);
            float var = sqs * (1.0f / 128.0f) - m * m;
            float inv = rsqrtf(var + 1e-5f);
            #pragma unroll
            for (int j = 0; j < 4; j++) {
                int col = wn + j * 16 + l16;
                float y = (acc[i][j][rg] - m) * inv * g[col] + bt[col];
                acc[i][j][rg] = y;
                if (EP == EP_LN1) {
                    outF[(size_t)row * 128 + col] = y;
                    outH[(size_t)row * 128 + col] = f2b(y);
                } else {
                    outH[(size_t)row * 128 + col] = f2b(y);
                }
            }
        }

    if (EP == EP_LN2HYP) {
        float* sred2 = (float*)Bs;
        #pragma unroll
        for (int i = 0; i < 4; i++)
            #pragma unroll
            for (int rg = 0; rg < 4; rg++) {
                float s2 = 0.f;
                #pragma unroll
                for (int j = 0; j < 4; j++) { float y = acc[i][j][rg]; s2 += y * y; }
                #pragma unroll
                for (int m = 1; m < 16; m <<= 1) s2 += __shfl_xor(s2, m, 64);
                if (l16 == 0) {
                    int rl = wm + i * 16 + q * 4 + rg;
                    sred2[rl * 2 + (wid & 1)] = s2;
                }
            }
        __syncthreads();
        #pragma unroll
        for (int i = 0; i < 4; i++)
            #pragma unroll
            for (int rg = 0; rg < 4; rg++) {
                int rl = wm + i * 16 + q * 4 + rg;
                int row = row0 + rl;
                float vn2 = sred2[rl * 2] + sred2[rl * 2 + 1];
                float vn = fmaxf(sqrtf(vn2), 1e-10f);
                float sc = tanhf(0.5f * sq * vn) / (sq * vn);
                float en2 = sc * sc * vn2;
                float en = sqrtf(en2);
                float f = fminf(mx / fmaxf(en, 1e-6f), 1.0f);
                float scale = sc * f;
                float e2v = en2 * f * f;
                #pragma unroll
                for (int j = 0; j < 4; j++) {
                    int col = wn + j * 16 + l16;
                    float e = acc[i][j][rg] * scale;
                    embF[(size_t)row * 128 + col] = e;
                    embH[(size_t)row * 128 + col] = f2b(e);
                }
                if (l16 == 0 && (wid & 1) == 0) {
                    e2a[row] = e2v;
                    dea[row] = 1.0f - c * fminf(e2v, 1.0f - 1e-5f);
                }
            }
    }
}

// --------------------------- fused heads (persistent col-loop) -------------
// grid (32, 16): block (bx, g) handles row-tile bx and col-tiles
//   hyp: cb = g, g+16, ... (<79)  then  euc: cb = g, g+16, ... (<79).
// A (128x128 bf16) lives in 64 VGPRs per thread (af[4][4]); B double-buffered
// in 64 KB LDS with counted-vmcnt 2-phase pipeline:
//   [wait vmcnt(32); barrier] -> MFMA(buf) -> epi(i=0,1: 32 stores)
//   -> stage next B (8 loads) -> epi(i=2,3: 32 stores) -> loop.
// At the next wait, exactly 32 stores are younger than the stage, so
// vmcnt(32) guarantees the stage retired (in-order vmcnt accounting).
// Partial tile cb==78 breaks the 32-store invariant -> next wait is vmcnt(0).
__global__ __launch_bounds__(256, 2) void k_heads(
    const unsigned short* __restrict__ embH, const unsigned short* __restrict__ tH,
    const unsigned short* __restrict__ protB, const unsigned short* __restrict__ eucWT,
    const float* __restrict__ e2a, const float* __restrict__ dea,
    const float* __restrict__ p2a, const float* __restrict__ dpa,
    const float* __restrict__ euc_b, const float* __restrict__ logc,
    float* __restrict__ outHyp, float* __restrict__ outEuc) {
    __shared__ __align__(16) unsigned short Bs[2][128 * 128];  // 2 x 32 KB
    const int tid = threadIdx.x, lane = tid & 63, wid = tid >> 6;
    const int row0 = blockIdx.x * 128, g = blockIdx.y;
    const int q = lane >> 4, l16 = lane & 15;
    const int wm = (wid >> 1) * 64, wn = (wid & 1) * 64;
    const int sw = (l16 & 7) * 8;
    const int nh = (94 - g) >> 4;  // ceil((79-g)/16)
    const int nt = 2 * nh;

    auto stageB = [&](int buf, int ti) {
        const unsigned short* Bp = (ti < nh) ? protB : eucWT;
        const int cb = (ti < nh) ? (g + 16 * ti) : (g + 16 * (ti - nh));
        const size_t c0 = (size_t)cb * 128;
        __builtin_amdgcn_sched_barrier(0);
        #pragma unroll
        for (int it = 0; it < 8; ++it) {
            int idx = it * 256 + tid;
            int r = idx >> 4, ck = (idx & 15) * 8;
            int cks = ck ^ ((r & 7) * 8);
            async16(&Bp[(c0 + r) * 128 + cks], &Bs[buf][idx * 8]);
        }
        __builtin_amdgcn_sched_barrier(0);
    };

    bf16x8 af[4][4];
    auto loadA = [&](const unsigned short* Ap) {
        #pragma unroll
        for (int i = 0; i < 4; i++)
            #pragma unroll
            for (int ks = 0; ks < 4; ks++)
                af[i][ks] = *(const bf16x8*)&Ap[
                    (size_t)(row0 + wm + i * 16 + l16) * 128 + ks * 32 + q * 8];
    };

    // ---- prologue: stage tile 0, A-regs, per-row params, one full drain ----
    stageB(0, 0);
    loadA(embH);
    float e2r[4][4], der[4][4];
    #pragma unroll
    for (int i = 0; i < 4; i++)
        #pragma unroll
        for (int rg = 0; rg < 4; rg++) {
            int row = row0 + wm + i * 16 + q * 4 + rg;
            e2r[i][rg] = e2a[row];
            der[i][rg] = dea[row];
        }
    const float c = get_c(logc);
    const float kmul = -2.0f / sqrtf(c);
    asm volatile("s_waitcnt vmcnt(0)" ::: "memory");
    __builtin_amdgcn_s_barrier();
    __builtin_amdgcn_sched_barrier(0);

    bool prev_partial = false;
    for (int ti = 0; ti < nt; ++ti) {
        if (ti > 0) {
            if (prev_partial) asm volatile("s_waitcnt vmcnt(0)" ::: "memory");
            else              asm volatile("s_waitcnt vmcnt(32)" ::: "memory");
            __builtin_amdgcn_s_barrier();
            __builtin_amdgcn_sched_barrier(0);
        }
        const bool isHyp = ti < nh;
        const int cb = isHyp ? (g + 16 * ti) : (g + 16 * (ti - nh));
        const int c0 = cb * 128;
        if (ti == nh) loadA(tH);  // switch A: emb -> t (once)

        // per-tile column params (issued before any stores -> older than stage)
        float pv[4], dv[4], bb[4];
        #pragma unroll
        for (int j = 0; j < 4; j++) {
            int col = c0 + wn + j * 16 + l16;
            if (isHyp) { pv[j] = p2a[col]; dv[j] = dpa[col]; }
            else       { bb[j] = (col < 10000) ? euc_b[col] : 0.0f; }
        }

        const int cur = ti & 1;
        f32x4 acc[4][4];
        #pragma unroll
        for (int i = 0; i < 4; i++)
            #pragma unroll
            for (int j = 0; j < 4; j++) acc[i][j] = {0.f, 0.f, 0.f, 0.f};
        #pragma unroll
        for (int ks = 0; ks < 4; ks++) {
            bf16x8 bfr[4];
            #pragma unroll
            for (int j = 0; j < 4; j++)
                bfr[j] = *(const bf16x8*)&Bs[cur][
                    (wn + j * 16 + l16) * 128 + ((ks * 32 + q * 8) ^ sw)];
            #pragma unroll
            for (int i = 0; i < 4; i++)
                #pragma unroll
                for (int j = 0; j < 4; j++)
                    acc[i][j] = __builtin_amdgcn_mfma_f32_16x16x32_bf16(
                        af[i][ks], bfr[j], acc[i][j], 0, 0, 0);
        }

        // epilogue: exactly 16 stores per thread per i (32 per half)
        auto epi = [&](int i) {
            #pragma unroll
            for (int rg = 0; rg < 4; rg++) {
                int row = row0 + wm + i * 16 + q * 4 + rg;
                #pragma unroll
                for (int j = 0; j < 4; j++) {
                    int col = c0 + wn + j * 16 + l16;
                    float v = acc[i][j][rg];
                    if (isHyp) {
                        float diff = fmaxf(fmaf(-2.0f, v, e2r[i][rg] + pv[j]), 1e-10f);
                        float den = fmaxf(der[i][rg] * dv[j], 1e-6f);
                        float arg = fmaf(2.0f * diff, __builtin_amdgcn_rcpf(den), 1.0f);
                        arg = fmaxf(arg, 1.0f + 1e-6f);
                        float t = __builtin_amdgcn_sqrtf(fmaf(arg, arg, -1.0f));
                        if (col < 10000)
                            outHyp[(size_t)row * 10000 + col] = kmul * __logf(arg + t);
                    } else {
                        if (col < 10000)
                            outEuc[(size_t)row * 10000 + col] = v + bb[j];
                    }
                }
            }
        };
        epi(0); epi(1);
        if (ti + 1 < nt) stageB(cur ^ 1, ti + 1);
        epi(2); epi(3);
        prev_partial = (c0 == 9984);  // cb==78: store count != 32 per half
    }
}

// --------------------------- launcher --------------------------------------

extern "C" void kernel_launch(void* const* d_in, const int* in_sizes, int n_in,
                              void* d_out, int out_size, void* d_ws, size_t ws_size,
                              hipStream_t stream) {
    const float* x      = (const float*)d_in[0];
    const float* W1     = (const float*)d_in[1];
    const float* b1     = (const float*)d_in[2];
    const float* W2     = (const float*)d_in[3];
    const float* b2     = (const float*)d_in[4];
    const float* in_w   = (const float*)d_in[5];
    const float* in_b   = (const float*)d_in[6];
    const float* out_w  = (const float*)d_in[7];
    const float* out_b  = (const float*)d_in[8];
    const float* fw1    = (const float*)d_in[9];
    const float* fb1    = (const float*)d_in[10];
    const float* fw2    = (const float*)d_in[11];
    const float* fb2    = (const float*)d_in[12];
    const float* g1     = (const float*)d_in[13];
    const float* bt1    = (const float*)d_in[14];
    const float* g2     = (const float*)d_in[15];
    const float* bt2    = (const float*)d_in[16];
    const float* logc   = (const float*)d_in[17];
    const float* protos = (const float*)d_in[18];
    const float* euc_w  = (const float*)d_in[19];
    const float* euc_b  = (const float*)d_in[20];

    float* out_hyp = (float*)d_out;
    float* out_euc = out_hyp + (size_t)4096 * 10000;
    float* out_emb = out_euc + (size_t)4096 * 10000;

    constexpr size_t O_XBF   = 0;                                   // 4096x1024 bf16
    constexpr size_t O_W1T   = O_XBF   + (size_t)4096 * 1024 * 2;   // 256x1024
    constexpr size_t O_FW1T  = O_W1T   + (size_t)256 * 1024 * 2;    // 512x128
    constexpr size_t O_FW2T  = O_FW1T  + (size_t)512 * 128 * 2;     // 128x512
    constexpr size_t O_EUCWT = O_FW2T  + (size_t)128 * 512 * 2;     // 10112x128
    constexpr size_t O_PROTB = O_EUCWT + (size_t)10112 * 128 * 2;   // 10112x128
    constexpr size_t O_W2PP  = O_PROTB + (size_t)10112 * 128 * 2;   // 128x256 bf16
    constexpr size_t O_BPP   = O_W2PP  + (size_t)128 * 256 * 2;     // 128 f32
    constexpr size_t O_HBF   = O_BPP   + (size_t)128 * 4;           // 4096x256 bf16
    constexpr size_t O_XS1F  = O_HBF   + (size_t)4096 * 256 * 2;    // 4096x128 f32
    constexpr size_t O_XS1B  = O_XS1F  + (size_t)4096 * 128 * 4;    // 4096x128 bf16
    constexpr size_t O_FHB   = O_XS1B  + (size_t)4096 * 128 * 2;    // 4096x512 bf16
    constexpr size_t O_TFB   = O_FHB   + (size_t)4096 * 512 * 2;    // 4096x128 bf16
    constexpr size_t O_EMBB  = O_TFB   + (size_t)4096 * 128 * 2;    // 4096x128 bf16
    constexpr size_t O_E2    = O_EMBB  + (size_t)4096 * 128 * 2;
    constexpr size_t O_DE    = O_E2    + (size_t)4096 * 4;
    constexpr size_t O_P2    = O_DE    + (size_t)4096 * 4;
    constexpr size_t O_DP    = O_P2    + (size_t)10112 * 4;

    char* w = (char*)d_ws;
    auto US = [&](size_t o) { return (unsigned short*)(w + o); };
    auto FP = [&](size_t o) { return (float*)(w + o); };

    k_prep<<<PB5, 256, 0, stream>>>(x, W1, fw1, fw2, euc_w, protos, logc,
                                    US(O_XBF), US(O_W1T), US(O_FW1T), US(O_FW2T),
                                    US(O_EUCWT), US(O_PROTB), FP(O_P2), FP(O_DP));
    k_fold<<<128, 128, 0, stream>>>(in_w, in_b, out_w, out_b, W2, b2,
                                    US(O_W2PP), FP(O_BPP));

    // GEMM1: gelu(x@W1+b1) -> h bf16 [4096x256]
    k_gemm<EP_GELU, 64><<<dim3(32, 2), 256, 0, stream>>>(
        US(O_XBF), US(O_W1T), b1, 1024, 256, nullptr, US(O_HBF),
        nullptr, nullptr, nullptr, nullptr, nullptr, nullptr, nullptr, nullptr);
    // GEMM2: h@W2''+b'' -> LN1 -> xs1 (f32 + bf16) [4096x128]
    k_gemm<EP_LN1, 64><<<dim3(32, 1), 256, 0, stream>>>(
        US(O_HBF), US(O_W2PP), FP(O_BPP), 256, 128, FP(O_XS1F), US(O_XS1B),
        g1, bt1, nullptr, nullptr, nullptr, nullptr, nullptr, nullptr);
    // FFN1: gelu(xs1@fw1+fb1) -> h2 bf16 [4096x512]
    k_gemm<EP_GELU, 128><<<dim3(32, 4), 256, 0, stream>>>(
        US(O_XS1B), US(O_FW1T), fb1, 128, 512, nullptr, US(O_FHB),
        nullptr, nullptr, nullptr, nullptr, nullptr, nullptr, nullptr, nullptr);
    // FFN2: xs1 + h2@fw2+fb2 -> LN2 -> t(bf16) + Poincare emb + e2/de
    k_gemm<EP_LN2HYP, 64><<<dim3(32, 1), 256, 0, stream>>>(
        US(O_FHB), US(O_FW2T), fb2, 512, 128, nullptr, US(O_TFB),
        g2, bt2, FP(O_XS1F), logc, out_emb, US(O_EMBB), FP(O_E2), FP(O_DE));
    // Heads: hyp (emb vs protos) + euc (t vs euc_w), persistent col-loop
    k_heads<<<dim3(32, 16), 256, 0, stream>>>(
        US(O_EMBB), US(O_TFB), US(O_PROTB), US(O_EUCWT),
        FP(O_E2), FP(O_DE), FP(O_P2), FP(O_DP), euc_b, logc, out_hyp, out_euc);
}

// Round 3
// 548.226 us; speedup vs baseline: 1.0902x; 1.0902x over previous
//
#include <hip/hip_runtime.h>
#include <cmath>

// ---------------------------------------------------------------------------
// HyperbolicScaleHead — round 5.
// Structure: softmax over seqlen-1 == identity => attn_out = t@(Wv@Wo)+b.
// Fold: pre1 = h @ (W2@(I+Wv@Wo)) + (b2@(I+Wv@Wo)+bc) -- one GEMM, LN1 fused.
// Pipeline (7 launches):
//   k_prep   : cvt x->bf16, transpose W1/fw1/fw2/euc_w, protos clip+norms
//   k_fold   : W2''^T = (W2@(I+Wv@Wo))^T bf16, b''
//   GEMM1    : gelu(x@W1+b1) -> bf16               (4096x256x1024)
//   GEMM2    : h@W2''+b'' -> LN1 epilogue          (4096x128x256)
//   FFN1     : gelu(xs1@fw1+fb1) -> bf16           (4096x512x128)
//   FFN2     : xs1 + h2@fw2+fb2 -> LN2+Poincare    (4096x128x512)
//   k_heads  : hyp + euc logits fused              (4096x(2x10112)x128)
// R5: k_heads occupancy fix. R4 post-mortem: k_heads=256us, Occupancy=1.2%,
//     VALUBusy=1.5% -> latency-bound (BW floor is ~72us for its 432MB).
//     Persistent design starved TLP (512 blocks) and its vmcnt(32) waited on
//     STORE retirement each tile. Now: grid (32,158) non-persistent, B-tile
//     only in LDS (32KB), A direct global->VGPR per k-slice (L2-resident),
//     __launch_bounds__(256,4) -> 4 blocks/CU, 16 waves/CU (2x R3, 4x R4
//     per-CU waves). No store waits. Fast-math arccosh epilogue kept.
// ---------------------------------------------------------------------------

using bf16x8 = __attribute__((ext_vector_type(8))) __bf16;
using f32x4  = __attribute__((ext_vector_type(4))) float;

#define DEVINL __device__ __forceinline__

DEVINL unsigned short f2b(float f) {
    unsigned int u = __builtin_bit_cast(unsigned int, f);
    u = (u + 0x7fffu + ((u >> 16) & 1u)) >> 16;
    return (unsigned short)u;
}

DEVINL float gelu_exact(float x) {
    return 0.5f * x * (1.0f + erff(x * 0.70710678118654752440f));
}

DEVINL float get_c(const float* logc) {
    float c = expf(logc[0]);
    c = fminf(fmaxf(c, 1e-4f), 10.0f);
    return fmaxf(fabsf(c), 1e-6f);
}

DEVINL void async16(const unsigned short* g, unsigned short* l) {
    __builtin_amdgcn_global_load_lds(
        (const __attribute__((address_space(1))) void*)g,
        (__attribute__((address_space(3))) void*)l, 16, 0, 0);
}

// --------------------------- prep mega-kernel ------------------------------

DEVINL void t_cvt(const float* __restrict__ src, unsigned short* __restrict__ dst,
                  int K, int N, int Npad, int ld, int off, int tblk, int tid,
                  float tile[32][33]) {
    int kbCount = K >> 5;
    int kb = (tblk % kbCount) * 32, nb = (tblk / kbCount) * 32;
    int tx = tid & 31, ty = tid >> 5;
    #pragma unroll
    for (int i = 0; i < 32; i += 8) {
        int k = kb + ty + i, n = nb + tx;
        tile[ty + i][tx] = (k < K && n < N) ? src[(size_t)k * ld + off + n] : 0.0f;
    }
    __syncthreads();
    // vectorized write-out: each thread writes ushort2 (2 consecutive k)
    int tx2 = (tid & 15) * 2, ty2 = tid >> 4;
    #pragma unroll
    for (int i = 0; i < 32; i += 16) {
        int n = nb + ty2 + i, k = kb + tx2;
        if (n < Npad) {  // K multiple of 32 -> k pair always in-range
            ushort2 o2;
            o2.x = f2b(tile[tx2][ty2 + i]);
            o2.y = f2b(tile[tx2 + 1][ty2 + i]);
            *(ushort2*)&dst[(size_t)n * K + k] = o2;
        }
    }
}

// block ranges: [0,4096) cvt x | +256 W1 | +64 fw1 | +64 fw2 | +1264 euc_w | +2528 protos
#define PB0 4096
#define PB1 (PB0 + 256)
#define PB2 (PB1 + 64)
#define PB3 (PB2 + 64)
#define PB4 (PB3 + 1264)
#define PB5 (PB4 + 2528)

__global__ void k_prep(const float* __restrict__ x, const float* __restrict__ W1,
                       const float* __restrict__ fw1, const float* __restrict__ fw2,
                       const float* __restrict__ euc_w, const float* __restrict__ P,
                       const float* __restrict__ logc,
                       unsigned short* __restrict__ xbf, unsigned short* __restrict__ W1T,
                       unsigned short* __restrict__ FW1T, unsigned short* __restrict__ FW2T,
                       unsigned short* __restrict__ EUCWT, unsigned short* __restrict__ PROTB,
                       float* __restrict__ p2a, float* __restrict__ dpa) {
    __shared__ float tile[32][33];
    int b = blockIdx.x, tid = threadIdx.x;
    if (b < PB0) {
        int i = b * 256 + tid;
        float4 v = ((const float4*)x)[i];
        ushort4 o;
        o.x = f2b(v.x); o.y = f2b(v.y); o.z = f2b(v.z); o.w = f2b(v.w);
        ((ushort4*)xbf)[i] = o;
    } else if (b < PB1) {
        t_cvt(W1, W1T, 1024, 256, 256, 256, 0, b - PB0, tid, tile);
    } else if (b < PB2) {
        t_cvt(fw1, FW1T, 128, 512, 512, 512, 0, b - PB1, tid, tile);
    } else if (b < PB3) {
        t_cvt(fw2, FW2T, 512, 128, 128, 128, 0, b - PB2, tid, tile);
    } else if (b < PB4) {
        t_cvt(euc_w, EUCWT, 128, 10000, 10112, 10000, 0, b - PB3, tid, tile);
    } else {
        int lane = tid & 63;
        int row = (b - PB4) * 4 + (tid >> 6);
        size_t base = (size_t)row * 128;
        if (row < 10000) {
            float a = P[base + lane], bb = P[base + 64 + lane];
            float n2 = a * a + bb * bb;
            #pragma unroll
            for (int m = 32; m > 0; m >>= 1) n2 += __shfl_xor(n2, m, 64);
            float c = get_c(logc);
            float sq = sqrtf(c);
            float mx = (1.0f - 1e-5f) / sq;
            float pn = sqrtf(n2);
            float f = fminf(mx / fmaxf(pn, 1e-6f), 1.0f);
            a *= f; bb *= f;
            PROTB[base + lane] = f2b(a); PROTB[base + 64 + lane] = f2b(bb);
            if (lane == 0) {
                float p2 = n2 * f * f;
                p2a[row] = p2;
                dpa[row] = 1.0f - c * fminf(p2, 1.0f - 1e-5f);
            }
        } else if (row < 10112) {
            PROTB[base + lane] = 0; PROTB[base + 64 + lane] = 0;
            if (lane == 0) { p2a[row] = 0.0f; dpa[row] = 1.0f; }
        }
    }
}

// --------------------------- fold kernel (merged) --------------------------
__global__ void k_fold(const float* __restrict__ in_w, const float* __restrict__ in_b,
                       const float* __restrict__ out_w, const float* __restrict__ out_b,
                       const float* __restrict__ W2, const float* __restrict__ b2,
                       unsigned short* __restrict__ W2ppT, float* __restrict__ bpp) {
    __shared__ float WoCol[128];
    __shared__ float WcCol[128];
    const int n = blockIdx.x, t = threadIdx.x;
    WoCol[t] = out_w[t * 128 + n];
    __syncthreads();
    float a = (t == n) ? 1.0f : 0.0f;
    for (int j = 0; j < 128; j++) a += in_w[t * 384 + 256 + j] * WoCol[j];
    WcCol[t] = a;
    __syncthreads();
    #pragma unroll
    for (int h = 0; h < 2; h++) {
        int k = t + h * 128;
        float s = 0.f;
        for (int j = 0; j < 128; j++) s += W2[k * 128 + j] * WcCol[j];
        W2ppT[n * 256 + k] = f2b(s);
    }
    if (t == 0) {
        float s = 0.f;
        for (int j = 0; j < 128; j++) s += b2[j] * WcCol[j];
        float s2 = 0.f;
        for (int j = 0; j < 128; j++) s2 += in_b[256 + j] * WoCol[j];
        bpp[n] = s + s2 + out_b[n];
    }
}

// --------------------------- GEMM + fused epilogues ------------------------
#define EP_GELU 0
#define EP_LN1 1
#define EP_LN2HYP 2

template <int EP, int BK>
__global__ __launch_bounds__(256) void k_gemm(
    const unsigned short* __restrict__ A, const unsigned short* __restrict__ Bm,
    const float* __restrict__ bias, int K, int Nstore,
    float* __restrict__ outF, unsigned short* __restrict__ outH,
    const float* __restrict__ g, const float* __restrict__ bt,
    const float* __restrict__ resF, const float* __restrict__ logc,
    float* __restrict__ embF, unsigned short* __restrict__ embH,
    float* __restrict__ e2a, float* __restrict__ dea) {
    __shared__ __align__(16) unsigned short As[128 * BK];
    __shared__ __align__(16) unsigned short Bs[128 * BK];
    const int tid = threadIdx.x, lane = tid & 63, wid = tid >> 6;
    const int row0 = blockIdx.x * 128, col0 = blockIdx.y * 128;
    const int q = lane >> 4, l16 = lane & 15;
    const int wm = (wid >> 1) * 64, wn = (wid & 1) * 64;
    const int sw = (l16 & 7) * 8;
    constexpr int CPR = BK / 8;
    constexpr int ITER = 128 * CPR / 256;

    f32x4 acc[4][4];
    #pragma unroll
    for (int i = 0; i < 4; i++)
        #pragma unroll
        for (int j = 0; j < 4; j++) acc[i][j] = {0.f, 0.f, 0.f, 0.f};

    for (int k0 = 0; k0 < K; k0 += BK) {
        #pragma unroll
        for (int it = 0; it < ITER; ++it) {
            int idx = it * 256 + tid;
            int r = idx / CPR, ck = (idx % CPR) * 8;
            int cks = ck ^ ((r & 7) * 8);
            async16(&A[(size_t)(row0 + r) * K + k0 + cks], &As[idx * 8]);
        }
        #pragma unroll
        for (int it = 0; it < ITER; ++it) {
            int idx = it * 256 + tid;
            int r = idx / CPR, ck = (idx % CPR) * 8;
            int cks = ck ^ ((r & 7) * 8);
            async16(&Bm[(size_t)(col0 + r) * K + k0 + cks], &Bs[idx * 8]);
        }
        __syncthreads();
        #pragma unroll
        for (int kk = 0; kk < BK; kk += 32) {
            bf16x8 af[4], bfr[4];
            #pragma unroll
            for (int i = 0; i < 4; i++)
                af[i] = *(const bf16x8*)&As[(wm + i * 16 + l16) * BK + ((kk + q * 8) ^ sw)];
            #pragma unroll
            for (int j = 0; j < 4; j++)
                bfr[j] = *(const bf16x8*)&Bs[(wn + j * 16 + l16) * BK + ((kk + q * 8) ^ sw)];
            #pragma unroll
            for (int i = 0; i < 4; i++)
                #pragma unroll
                for (int j = 0; j < 4; j++)
                    acc[i][j] = __builtin_amdgcn_mfma_f32_16x16x32_bf16(
                        af[i], bfr[j], acc[i][j], 0, 0, 0);
        }
        __syncthreads();
    }

    if (EP == EP_GELU) {
        #pragma unroll
        for (int j = 0; j < 4; j++) {
            int col = col0 + wn + j * 16 + l16;
            float bb = bias[col];
            #pragma unroll
            for (int i = 0; i < 4; i++)
                #pragma unroll
                for (int rg = 0; rg < 4; rg++) {
                    int row = row0 + wm + i * 16 + q * 4 + rg;
                    outH[(size_t)row * Nstore + col] = f2b(gelu_exact(acc[i][j][rg] + bb));
                }
        }
        return;
    }

    #pragma unroll
    for (int j = 0; j < 4; j++) {
        int col = wn + j * 16 + l16;
        float bb = bias[col];
        #pragma unroll
        for (int i = 0; i < 4; i++)
            #pragma unroll
            for (int rg = 0; rg < 4; rg++) {
                int rl = wm + i * 16 + q * 4 + rg;
                float v = acc[i][j][rg] + bb;
                if (EP == EP_LN2HYP) v += resF[(size_t)(row0 + rl) * 128 + col];
                acc[i][j][rg] = v;
            }
    }
    float* sred = (float*)As;
    #pragma unroll
    for (int i = 0; i < 4; i++)
        #pragma unroll
        for (int rg = 0; rg < 4; rg++) {
            float s = 0.f, ss = 0.f;
            #pragma unroll
            for (int j = 0; j < 4; j++) { float v = acc[i][j][rg]; s += v; ss += v * v; }
            #pragma unroll
            for (int m = 1; m < 16; m <<= 1) {
                s += __shfl_xor(s, m, 64); ss += __shfl_xor(ss, m, 64);
            }
            if (l16 == 0) {
                int rl = wm + i * 16 + q * 4 + rg;
                sred[rl * 4 + (wid & 1) * 2] = s;
                sred[rl * 4 + (wid & 1) * 2 + 1] = ss;
            }
        }
    __syncthreads();

    float c = 0.f, sq = 0.f, mx = 0.f;
    if (EP == EP_LN2HYP) { c = get_c(logc); sq = sqrtf(c); mx = (1.0f - 1e-5f) / sq; }

    #pragma unroll
    for (int i = 0; i < 4; i++)
        #pragma unroll
        for (int rg = 0; rg < 4; rg++) {
            int rl = wm + i * 16 + q * 4 + rg;
            int row = row0 + rl;
            float sum = sred[rl * 4 + 0] + sred[rl * 4 + 2];
            float sqs = sred[rl * 4 + 1] + sred[rl * 4 + 3];
            float m = sum * (1.0f / 128.0f);
            float var = sqs * (1.0f / 128.0f) - m * m;
            float inv = rsqrtf(var + 1e-5f);
            #pragma unroll
            for (int j = 0; j < 4; j++) {
                int col = wn + j * 16 + l16;
                float y = (acc[i][j][rg] - m) * inv * g[col] + bt[col];
                acc[i][j][rg] = y;
                if (EP == EP_LN1) {
                    outF[(size_t)row * 128 + col] = y;
                    outH[(size_t)row * 128 + col] = f2b(y);
                } else {
                    outH[(size_t)row * 128 + col] = f2b(y);
                }
            }
        }

    if (EP == EP_LN2HYP) {
        float* sred2 = (float*)Bs;
        #pragma unroll
        for (int i = 0; i < 4; i++)
            #pragma unroll
            for (int rg = 0; rg < 4; rg++) {
                float s2 = 0.f;
                #pragma unroll
                for (int j = 0; j < 4; j++) { float y = acc[i][j][rg]; s2 += y * y; }
                #pragma unroll
                for (int m = 1; m < 16; m <<= 1) s2 += __shfl_xor(s2, m, 64);
                if (l16 == 0) {
                    int rl = wm + i * 16 + q * 4 + rg;
                    sred2[rl * 2 + (wid & 1)] = s2;
                }
            }
        __syncthreads();
        #pragma unroll
        for (int i = 0; i < 4; i++)
            #pragma unroll
            for (int rg = 0; rg < 4; rg++) {
                int rl = wm + i * 16 + q * 4 + rg;
                int row = row0 + rl;
                float vn2 = sred2[rl * 2] + sred2[rl * 2 + 1];
                float vn = fmaxf(sqrtf(vn2), 1e-10f);
                float sc = tanhf(0.5f * sq * vn) / (sq * vn);
                float en2 = sc * sc * vn2;
                float en = sqrtf(en2);
                float f = fminf(mx / fmaxf(en, 1e-6f), 1.0f);
                float scale = sc * f;
                float e2v = en2 * f * f;
                #pragma unroll
                for (int j = 0; j < 4; j++) {
                    int col = wn + j * 16 + l16;
                    float e = acc[i][j][rg] * scale;
                    embF[(size_t)row * 128 + col] = e;
                    embH[(size_t)row * 128 + col] = f2b(e);
                }
                if (l16 == 0 && (wid & 1) == 0) {
                    e2a[row] = e2v;
                    dea[row] = 1.0f - c * fminf(e2v, 1.0f - 1e-5f);
                }
            }
    }
}

// --------------------------- fused heads -----------------------------------
// grid (32, 158): y<79 -> hyperbolic head, else euclidean. K=128 single-stage.
// B tile in 32KB LDS (swizzled). A direct global->VGPR per k-slice (A is
// 2MB total, L2-resident after 1st generation). 4 blocks/CU (16 waves/CU).
__global__ __launch_bounds__(256, 4) void k_heads(
    const unsigned short* __restrict__ embH, const unsigned short* __restrict__ tH,
    const unsigned short* __restrict__ protB, const unsigned short* __restrict__ eucWT,
    const float* __restrict__ e2a, const float* __restrict__ dea,
    const float* __restrict__ p2a, const float* __restrict__ dpa,
    const float* __restrict__ euc_b, const float* __restrict__ logc,
    float* __restrict__ outHyp, float* __restrict__ outEuc) {
    __shared__ __align__(16) unsigned short Bs[128 * 128];  // 32 KB
    const bool hyp = blockIdx.y < 79;
    const int cb = hyp ? blockIdx.y : blockIdx.y - 79;
    const unsigned short* Ap = hyp ? embH : tH;
    const unsigned short* Bp = hyp ? protB : eucWT;
    const int tid = threadIdx.x, lane = tid & 63, wid = tid >> 6;
    const int row0 = blockIdx.x * 128, c0 = cb * 128;
    const int q = lane >> 4, l16 = lane & 15;
    const int wm = (wid >> 1) * 64, wn = (wid & 1) * 64;
    const int sw = (l16 & 7) * 8;

    // stage B -> LDS (swizzled source, linear dest)
    #pragma unroll
    for (int it = 0; it < 8; ++it) {
        int idx = it * 256 + tid;
        int r = idx >> 4, ck = (idx & 15) * 8;
        int cks = ck ^ ((r & 7) * 8);
        async16(&Bp[(size_t)(c0 + r) * 128 + cks], &Bs[idx * 8]);
    }
    __syncthreads();  // drains vmcnt -> Bs ready

    f32x4 acc[4][4];
    #pragma unroll
    for (int i = 0; i < 4; i++)
        #pragma unroll
        for (int j = 0; j < 4; j++) acc[i][j] = {0.f, 0.f, 0.f, 0.f};

    const size_t arow = (size_t)(row0 + wm + l16) * 128 + q * 8;
    #pragma unroll
    for (int ks = 0; ks < 4; ks++) {
        bf16x8 af[4];
        #pragma unroll
        for (int i = 0; i < 4; i++)
            af[i] = *(const bf16x8*)&Ap[arow + (size_t)i * 16 * 128 + ks * 32];
        #pragma unroll
        for (int j = 0; j < 4; j++) {
            bf16x8 b8 = *(const bf16x8*)&Bs[
                (wn + j * 16 + l16) * 128 + ((ks * 32 + q * 8) ^ sw)];
            #pragma unroll
            for (int i = 0; i < 4; i++)
                acc[i][j] = __builtin_amdgcn_mfma_f32_16x16x32_bf16(
                    af[i], b8, acc[i][j], 0, 0, 0);
        }
    }

    if (hyp) {
        const float c = get_c(logc);
        const float kmul = -2.0f / sqrtf(c);
        float pv[4], dv[4], e2r[4][4], der[4][4];
        #pragma unroll
        for (int j = 0; j < 4; j++) {
            int col = c0 + wn + j * 16 + l16;  // p2a/dpa padded to 10112
            pv[j] = p2a[col]; dv[j] = dpa[col];
        }
        #pragma unroll
        for (int i = 0; i < 4; i++)
            #pragma unroll
            for (int rg = 0; rg < 4; rg++) {
                int row = row0 + wm + i * 16 + q * 4 + rg;
                e2r[i][rg] = e2a[row]; der[i][rg] = dea[row];
            }
        #pragma unroll
        for (int i = 0; i < 4; i++)
            #pragma unroll
            for (int rg = 0; rg < 4; rg++) {
                int row = row0 + wm + i * 16 + q * 4 + rg;
                #pragma unroll
                for (int j = 0; j < 4; j++) {
                    int col = c0 + wn + j * 16 + l16;
                    float v = acc[i][j][rg];
                    float diff = fmaxf(fmaf(-2.0f, v, e2r[i][rg] + pv[j]), 1e-10f);
                    float den = fmaxf(der[i][rg] * dv[j], 1e-6f);
                    float arg = fmaf(2.0f * diff, __builtin_amdgcn_rcpf(den), 1.0f);
                    arg = fmaxf(arg, 1.0f + 1e-6f);
                    float t = __builtin_amdgcn_sqrtf(fmaf(arg, arg, -1.0f));
                    if (col < 10000)
                        outHyp[(size_t)row * 10000 + col] = kmul * __logf(arg + t);
                }
            }
    } else {
        float bb[4];
        #pragma unroll
        for (int j = 0; j < 4; j++) {
            int col = c0 + wn + j * 16 + l16;
            bb[j] = (col < 10000) ? euc_b[col] : 0.0f;
        }
        #pragma unroll
        for (int i = 0; i < 4; i++)
            #pragma unroll
            for (int rg = 0; rg < 4; rg++) {
                int row = row0 + wm + i * 16 + q * 4 + rg;
                #pragma unroll
                for (int j = 0; j < 4; j++) {
                    int col = c0 + wn + j * 16 + l16;
                    if (col < 10000)
                        outEuc[(size_t)row * 10000 + col] = acc[i][j][rg] + bb[j];
                }
            }
    }
}

// --------------------------- launcher --------------------------------------

extern "C" void kernel_launch(void* const* d_in, const int* in_sizes, int n_in,
                              void* d_out, int out_size, void* d_ws, size_t ws_size,
                              hipStream_t stream) {
    const float* x      = (const float*)d_in[0];
    const float* W1     = (const float*)d_in[1];
    const float* b1     = (const float*)d_in[2];
    const float* W2     = (const float*)d_in[3];
    const float* b2     = (const float*)d_in[4];
    const float* in_w   = (const float*)d_in[5];
    const float* in_b   = (const float*)d_in[6];
    const float* out_w  = (const float*)d_in[7];
    const float* out_b  = (const float*)d_in[8];
    const float* fw1    = (const float*)d_in[9];
    const float* fb1    = (const float*)d_in[10];
    const float* fw2    = (const float*)d_in[11];
    const float* fb2    = (const float*)d_in[12];
    const float* g1     = (const float*)d_in[13];
    const float* bt1    = (const float*)d_in[14];
    const float* g2     = (const float*)d_in[15];
    const float* bt2    = (const float*)d_in[16];
    const float* logc   = (const float*)d_in[17];
    const float* protos = (const float*)d_in[18];
    const float* euc_w  = (const float*)d_in[19];
    const float* euc_b  = (const float*)d_in[20];

    float* out_hyp = (float*)d_out;
    float* out_euc = out_hyp + (size_t)4096 * 10000;
    float* out_emb = out_euc + (size_t)4096 * 10000;

    constexpr size_t O_XBF   = 0;                                   // 4096x1024 bf16
    constexpr size_t O_W1T   = O_XBF   + (size_t)4096 * 1024 * 2;   // 256x1024
    constexpr size_t O_FW1T  = O_W1T   + (size_t)256 * 1024 * 2;    // 512x128
    constexpr size_t O_FW2T  = O_FW1T  + (size_t)512 * 128 * 2;     // 128x512
    constexpr size_t O_EUCWT = O_FW2T  + (size_t)128 * 512 * 2;     // 10112x128
    constexpr size_t O_PROTB = O_EUCWT + (size_t)10112 * 128 * 2;   // 10112x128
    constexpr size_t O_W2PP  = O_PROTB + (size_t)10112 * 128 * 2;   // 128x256 bf16
    constexpr size_t O_BPP   = O_W2PP  + (size_t)128 * 256 * 2;     // 128 f32
    constexpr size_t O_HBF   = O_BPP   + (size_t)128 * 4;           // 4096x256 bf16
    constexpr size_t O_XS1F  = O_HBF   + (size_t)4096 * 256 * 2;    // 4096x128 f32
    constexpr size_t O_XS1B  = O_XS1F  + (size_t)4096 * 128 * 4;    // 4096x128 bf16
    constexpr size_t O_FHB   = O_XS1B  + (size_t)4096 * 128 * 2;    // 4096x512 bf16
    constexpr size_t O_TFB   = O_FHB   + (size_t)4096 * 512 * 2;    // 4096x128 bf16
    constexpr size_t O_EMBB  = O_TFB   + (size_t)4096 * 128 * 2;    // 4096x128 bf16
    constexpr size_t O_E2    = O_EMBB  + (size_t)4096 * 128 * 2;
    constexpr size_t O_DE    = O_E2    + (size_t)4096 * 4;
    constexpr size_t O_P2    = O_DE    + (size_t)4096 * 4;
    constexpr size_t O_DP    = O_P2    + (size_t)10112 * 4;

    char* w = (char*)d_ws;
    auto US = [&](size_t o) { return (unsigned short*)(w + o); };
    auto FP = [&](size_t o) { return (float*)(w + o); };

    k_prep<<<PB5, 256, 0, stream>>>(x, W1, fw1, fw2, euc_w, protos, logc,
                                    US(O_XBF), US(O_W1T), US(O_FW1T), US(O_FW2T),
                                    US(O_EUCWT), US(O_PROTB), FP(O_P2), FP(O_DP));
    k_fold<<<128, 128, 0, stream>>>(in_w, in_b, out_w, out_b, W2, b2,
                                    US(O_W2PP), FP(O_BPP));

    // GEMM1: gelu(x@W1+b1) -> h bf16 [4096x256]
    k_gemm<EP_GELU, 64><<<dim3(32, 2), 256, 0, stream>>>(
        US(O_XBF), US(O_W1T), b1, 1024, 256, nullptr, US(O_HBF),
        nullptr, nullptr, nullptr, nullptr, nullptr, nullptr, nullptr, nullptr);
    // GEMM2: h@W2''+b'' -> LN1 -> xs1 (f32 + bf16) [4096x128]
    k_gemm<EP_LN1, 64><<<dim3(32, 1), 256, 0, stream>>>(
        US(O_HBF), US(O_W2PP), FP(O_BPP), 256, 128, FP(O_XS1F), US(O_XS1B),
        g1, bt1, nullptr, nullptr, nullptr, nullptr, nullptr, nullptr);
    // FFN1: gelu(xs1@fw1+fb1) -> h2 bf16 [4096x512]
    k_gemm<EP_GELU, 128><<<dim3(32, 4), 256, 0, stream>>>(
        US(O_XS1B), US(O_FW1T), fb1, 128, 512, nullptr, US(O_FHB),
        nullptr, nullptr, nullptr, nullptr, nullptr, nullptr, nullptr, nullptr);
    // FFN2: xs1 + h2@fw2+fb2 -> LN2 -> t(bf16) + Poincare emb + e2/de
    k_gemm<EP_LN2HYP, 64><<<dim3(32, 1), 256, 0, stream>>>(
        US(O_FHB), US(O_FW2T), fb2, 512, 128, nullptr, US(O_TFB),
        g2, bt2, FP(O_XS1F), logc, out_emb, US(O_EMBB), FP(O_E2), FP(O_DE));
    // Heads: hyp (emb vs protos) + euc (t vs euc_w), fused
    k_heads<<<dim3(32, 158), 256, 0, stream>>>(
        US(O_EMBB), US(O_TFB), US(O_PROTB), US(O_EUCWT),
        FP(O_E2), FP(O_DE), FP(O_P2), FP(O_DP), euc_b, logc, out_hyp, out_euc);
}